// Round 3
// baseline (29024.503 us; speedup 1.0000x reference)
//
#include <hip/hip_runtime.h>
#include <cstdint>
#include <cstddef>

typedef __attribute__((ext_vector_type(8))) short short8;
typedef __attribute__((ext_vector_type(4))) short short4v;
typedef __attribute__((ext_vector_type(4))) float f32x4;

#define TT 2048
#define BB 32
#define HH 512

__device__ inline short f2bf(float f) {
  union { float f; unsigned u; } v; v.f = f;
  unsigned r = v.u + 0x7fffu + ((v.u >> 16) & 1u);
  return (short)(r >> 16);
}
__device__ inline float bf2f(short s) {
  union { unsigned u; float f; } v; v.u = ((unsigned)(unsigned short)s) << 16;
  return v.f;
}

// xin swizzled element index for (t, b, c):
//   wg=b>>4, bl=b&15(=l16), wv=c>>6, ct=(c>>4)&3, q=(c>>2)&3, r=c&3, lane=q*16+bl
//   idx = ((((t*2+wg)*8+wv)*4+ct)*64 + lane)*4 + r

// ---------------- weight fp32 -> bf16 conversion ----------------
__global__ void convert_weights(const float* __restrict__ w0, const float* __restrict__ w1,
                                const float* __restrict__ w2, const float* __restrict__ w3,
                                const float* __restrict__ w4, short* __restrict__ dst) {
  int i = blockIdx.x * 256 + threadIdx.x;
  if (i >= 1048576) return;
  const float* src; int off;
  if (i < 131072)      { src = w0; off = i; }
  else if (i < 393216) { src = w1; off = i - 131072; }
  else if (i < 655360) { src = w2; off = i - 393216; }
  else if (i < 917504) { src = w3; off = i - 655360; }
  else                 { src = w4; off = i - 917504; }
  dst[i] = f2bf(src[off]);
}

// ---------------- bf16 MFMA GEMM, C = A @ B^T + bias ----------------
// A_XF32: A is fp32 x[b][t][K] with logical row m = t*32+b (remapped load)
// OUT_SW: write bf16 into swizzled xin layout; else fp32 [b][t][N] (+resid x)
template<int A_XF32, int OUT_SW, int RESID>
__global__ __launch_bounds__(256) void gemm_bt(const void* __restrict__ Ap,
    const short* __restrict__ Bw, const float* __restrict__ bias,
    const float* __restrict__ resid, void* __restrict__ Cp, int M, int N, int K) {
  __shared__ short As[64][40];
  __shared__ short Bs[64][40];
  int tid = threadIdx.x;
  int m0 = blockIdx.x * 64, n0 = blockIdx.y * 64;
  int w = tid >> 6, lane = tid & 63;
  int wm = w >> 1, wn = w & 1;
  int quad = lane >> 4, l16 = lane & 15;
  f32x4 acc[2][2];
#pragma unroll
  for (int i = 0; i < 2; i++)
#pragma unroll
    for (int j = 0; j < 2; j++) acc[i][j] = (f32x4){0.f, 0.f, 0.f, 0.f};
  int lr = tid >> 2, lk = (tid & 3) * 8;
  for (int kk = 0; kk < K; kk += 32) {
    __syncthreads();
    {
      int rl = m0 + lr;
      if (A_XF32) {
        const float* A = (const float*)Ap;
        size_t phys = ((size_t)(rl & 31) * TT + (rl >> 5)) * K;
        const float4* p = (const float4*)(A + phys + kk + lk);
        float4 a0 = p[0], a1 = p[1];
        short8 v;
        v[0] = f2bf(a0.x); v[1] = f2bf(a0.y); v[2] = f2bf(a0.z); v[3] = f2bf(a0.w);
        v[4] = f2bf(a1.x); v[5] = f2bf(a1.y); v[6] = f2bf(a1.z); v[7] = f2bf(a1.w);
        *(short8*)&As[lr][lk] = v;
      } else {
        const short* A = (const short*)Ap;
        *(short8*)&As[lr][lk] = *(const short8*)(A + (size_t)rl * K + kk + lk);
      }
      *(short8*)&Bs[lr][lk] = *(const short8*)(Bw + (size_t)(n0 + lr) * K + kk + lk);
    }
    __syncthreads();
    short8 af[2], bfr[2];
#pragma unroll
    for (int i = 0; i < 2; i++) af[i] = *(short8*)&As[wm * 32 + i * 16 + l16][quad * 8];
#pragma unroll
    for (int j = 0; j < 2; j++) bfr[j] = *(short8*)&Bs[wn * 32 + j * 16 + l16][quad * 8];
#pragma unroll
    for (int i = 0; i < 2; i++)
#pragma unroll
      for (int j = 0; j < 2; j++)
        acc[i][j] = __builtin_amdgcn_mfma_f32_16x16x32_bf16(af[i], bfr[j], acc[i][j], 0, 0, 0);
  }
#pragma unroll
  for (int i = 0; i < 2; i++) {
#pragma unroll
    for (int j = 0; j < 2; j++) {
#pragma unroll
      for (int rr = 0; rr < 4; rr++) {
        int row = m0 + wm * 32 + i * 16 + quad * 4 + rr;
        int col = n0 + wn * 32 + j * 16 + l16;
        float v2 = acc[i][j][rr] + bias[col];
        if (OUT_SW) {
          int t = row >> 5, b = row & 31;
          int wg2 = b >> 4, bl = b & 15;
          int wv2 = col >> 6, ct2 = (col >> 4) & 3, q2 = (col >> 2) & 3, r2 = col & 3;
          size_t idx = (((((size_t)t * 2 + wg2) * 8 + wv2) * 4 + ct2) * 64 + (q2 * 16 + bl)) * 4 + r2;
          ((short*)Cp)[idx] = f2bf(v2);
        } else {
          size_t idx = ((size_t)(row & 31) * TT + (row >> 5)) * N + col;
          if (RESID) v2 += resid[idx];
          ((float*)Cp)[idx] = v2;
        }
      }
    }
  }
}

// ---------------- single-CU-per-batch-group CT-RNN scan ----------------
// 2 WGs x 512 threads. WG wg owns batches [wg*16, wg*16+16), ALL 512 cols.
// Full W_rec resident in registers (64 frags = 256 AGPRs/wave).
// MFMA operands swapped: A=W (m=col), B=h (n=batch) -> thread holds 4
// consecutive h-cols per ct => vectorized LDS writes + reg->global hall store.
// hb double-buffered => ONE barrier per step.
__global__ __launch_bounds__(512, 2) void seq_scan(
    const short* __restrict__ xin_sw, const short* __restrict__ Wrec,
    const float* __restrict__ tau, short* __restrict__ hall) {
  __shared__ __align__(16) short hb[2][16][520];
  int wg = blockIdx.x;
  int tid = threadIdx.x;
  int wv = tid >> 6, lane = tid & 63;
  int q = lane >> 4, l16 = lane & 15;
  int c0 = wv * 64;

  for (int i = tid; i < 2 * 16 * 520 / 2; i += 512) ((int*)hb)[i] = 0;

  // 64 weight fragments, all in registers (AGPR): frag(ct,kc) = A-operand
  // A[m=l16][k=q*8+j] for col-tile m = c0+ct*16+l16, k-chunk kc.
  short8 wreg[64];
#pragma unroll
  for (int ct = 0; ct < 4; ct++) {
    const short* wrow = Wrec + (size_t)(c0 + ct * 16 + l16) * HH;
#pragma unroll
    for (int kc = 0; kc < 16; kc++)
      wreg[ct * 16 + kc] = *(const short8*)(wrow + kc * 32 + q * 8);
  }
  // per-thread rates for its 16 cols (ct, r): col = c0 + ct*16 + q*4 + r
  float rate[16];
#pragma unroll
  for (int ct = 0; ct < 4; ct++)
#pragma unroll
    for (int r = 0; r < 4; r++) {
      float tc = tau[c0 + ct * 16 + q * 4 + r];
      tc = fminf(fmaxf(tc, 0.1f), 10.f);
      rate[ct * 4 + r] = 0.1f / tc;
    }
  float st[16];
#pragma unroll
  for (int i = 0; i < 16; i++) st[i] = 0.f;
  short4v hpk[4];
#pragma unroll
  for (int ct = 0; ct < 4; ct++) hpk[ct] = (short4v){0, 0, 0, 0};

  const short* xbase = xin_sw + (size_t)wg * 8192 + wv * 1024 + lane * 4;
  short* hallp = hall + ((size_t)wg * 16 + l16) * HH + c0 + q * 4;

  short4v xr[4];
#pragma unroll
  for (int ct = 0; ct < 4; ct++) xr[ct] = *(const short4v*)(xbase + ct * 256);
  __syncthreads();

  int cur = 0;
  for (int t = 0; t < TT; t++) {
    // prefetch xin for t+1 (issued ~full step before use/drain)
    int tn = (t + 1 < TT) ? t + 1 : t;
    const short* xp = xbase + (size_t)tn * 16384;
    short4v xn[4];
#pragma unroll
    for (int ct = 0; ct < 4; ct++) xn[ct] = *(const short4v*)(xp + ct * 256);
    // store h(t) (computed last iteration, packed in hpk) to hall row t-1
    if (t > 0) {
      short* hp = hallp + ((size_t)(t - 1) * 32) * HH;
#pragma unroll
      for (int ct = 0; ct < 4; ct++) *(short4v*)(hp + ct * 16) = hpk[ct];
    }
    // matvec: D[m=col][n=batch] over K=512
    f32x4 acc[4];
#pragma unroll
    for (int ct = 0; ct < 4; ct++) acc[ct] = (f32x4){0.f, 0.f, 0.f, 0.f};
#pragma unroll
    for (int kc = 0; kc < 16; kc++) {
      short8 af = *(short8*)&hb[cur][l16][kc * 32 + q * 8];
#pragma unroll
      for (int ct = 0; ct < 4; ct++)
        acc[ct] = __builtin_amdgcn_mfma_f32_16x16x32_bf16(wreg[ct * 16 + kc], af, acc[ct], 0, 0, 0);
    }
    // epilogue: thread holds batch=l16, cols c0+ct*16+q*4+r
#pragma unroll
    for (int ct = 0; ct < 4; ct++) {
      short4v hv;
#pragma unroll
      for (int r = 0; r < 4; r++) {
        float u = acc[ct][r] + bf2f(xr[ct][r]);
        float v = u * 2.8853900817779268f;          // 2*log2(e)*u
        v = fminf(fmaxf(v, -30.f), 30.f);
        float e = __builtin_amdgcn_exp2f(v);
        float tg = (e - 1.f) * __builtin_amdgcn_rcpf(e + 1.f);
        float h = st[ct * 4 + r];
        h += rate[ct * 4 + r] * (tg - h);
        st[ct * 4 + r] = h;
        hv[r] = f2bf(h);
      }
      hpk[ct] = hv;
      *(short4v*)&hb[cur ^ 1][l16][c0 + ct * 16 + q * 4] = hv;
      xr[ct] = xn[ct];
    }
    __syncthreads();   // hb[cur^1] complete; next iter reads it
    cur ^= 1;
  }
  // final hall row (h after step TT-1)
  {
    short* hp = hallp + ((size_t)(TT - 1) * 32) * HH;
#pragma unroll
    for (int ct = 0; ct < 4; ct++) *(short4v*)(hp + ct * 16) = hpk[ct];
  }
}

extern "C" void kernel_launch(void* const* d_in, const int* in_sizes, int n_in,
                              void* d_out, int out_size, void* d_ws, size_t ws_size,
                              hipStream_t stream) {
  const float* x      = (const float*)d_in[0];
  const float* W_in0  = (const float*)d_in[1];
  const float* b_in0  = (const float*)d_in[2];
  const float* W_rec0 = (const float*)d_in[3];
  const float* tau0   = (const float*)d_in[4];
  const float* W_in1  = (const float*)d_in[5];
  const float* b_in1  = (const float*)d_in[6];
  const float* W_rec1 = (const float*)d_in[7];
  const float* tau1   = (const float*)d_in[8];
  const float* W_out  = (const float*)d_in[9];
  const float* b_out  = (const float*)d_in[10];

  char* ws = (char*)d_ws;
  short* wb     = (short*)ws;                        // 2 MB bf16 weights
  short* xin_sw = (short*)(ws + (4u << 20));         // 64 MB swizzled xin
  short* hall   = (short*)(ws + (68u << 20));        // 64 MB h stream (t-major)

  short* wbin0  = wb;
  short* wbrec0 = wb + 131072;
  short* wbin1  = wb + 393216;
  short* wbrec1 = wb + 655360;
  short* wbout  = wb + 917504;

  convert_weights<<<4096, 256, 0, stream>>>(W_in0, W_rec0, W_in1, W_rec1, W_out, wb);

  dim3 g1(1024, 8);
  // xin0 = x @ W_in0^T + b_in0  (swizzled bf16)
  gemm_bt<1, 1, 0><<<g1, 256, 0, stream>>>((const void*)x, wbin0, b_in0, nullptr,
                                           (void*)xin_sw, BB * TT, HH, 256);
  // layer-0 scan -> hall (h0, time-major)
  seq_scan<<<2, 512, 0, stream>>>(xin_sw, wbrec0, tau0, hall);
  // xin1 = h0 @ W_in1^T + b_in1  (swizzled bf16)
  gemm_bt<0, 1, 0><<<g1, 256, 0, stream>>>((const void*)hall, wbin1, b_in1, nullptr,
                                           (void*)xin_sw, BB * TT, HH, HH);
  // layer-1 scan -> hall (h1)
  seq_scan<<<2, 512, 0, stream>>>(xin_sw, wbrec1, tau1, hall);
  // out = h1 @ W_out^T + b_out + x  (fp32, [b][t][c])
  dim3 g2(1024, 4);
  gemm_bt<0, 0, 1><<<g2, 256, 0, stream>>>((const void*)hall, wbout, b_out, x,
                                           d_out, BB * TT, 256, HH);
}

// Round 4
// 14019.019 us; speedup vs baseline: 2.0704x; 2.0704x over previous
//
#include <hip/hip_runtime.h>
#include <cstdint>
#include <cstddef>

typedef __attribute__((ext_vector_type(8))) short short8;
typedef __attribute__((ext_vector_type(4))) short short4v;
typedef __attribute__((ext_vector_type(4))) float f32x4;

#define TT 2048
#define BB 32
#define HH 512

__device__ inline short f2bf(float f) {
  union { float f; unsigned u; } v; v.f = f;
  unsigned r = v.u + 0x7fffu + ((v.u >> 16) & 1u);
  return (short)(r >> 16);
}
__device__ inline float bf2f(short s) {
  union { unsigned u; float f; } v; v.u = ((unsigned)(unsigned short)s) << 16;
  return v.f;
}

// LDS-only barrier: drains ds ops (lgkmcnt) but NOT global loads/stores
// (vmcnt), so xin prefetches and hall stores stay in flight across steps.
__device__ inline void barrier_lds() {
  asm volatile("s_waitcnt lgkmcnt(0)\n\ts_barrier" ::: "memory");
}

// xin swizzled element index for (t, b, c):
//   wg=b>>4, bl=b&15(=l16), wv=c>>6, ct=(c>>4)&3, q=(c>>2)&3, r=c&3, lane=q*16+bl
//   idx = ((((t*2+wg)*8+wv)*4+ct)*64 + lane)*4 + r

// ---------------- weight fp32 -> bf16 conversion ----------------
__global__ void convert_weights(const float* __restrict__ w0, const float* __restrict__ w1,
                                const float* __restrict__ w2, const float* __restrict__ w3,
                                const float* __restrict__ w4, short* __restrict__ dst) {
  int i = blockIdx.x * 256 + threadIdx.x;
  if (i >= 1048576) return;
  const float* src; int off;
  if (i < 131072)      { src = w0; off = i; }
  else if (i < 393216) { src = w1; off = i - 131072; }
  else if (i < 655360) { src = w2; off = i - 393216; }
  else if (i < 917504) { src = w3; off = i - 655360; }
  else                 { src = w4; off = i - 917504; }
  dst[i] = f2bf(src[off]);
}

// ---------------- bf16 MFMA GEMM, C = A @ B^T + bias ----------------
template<int A_XF32, int OUT_SW, int RESID>
__global__ __launch_bounds__(256) void gemm_bt(const void* __restrict__ Ap,
    const short* __restrict__ Bw, const float* __restrict__ bias,
    const float* __restrict__ resid, void* __restrict__ Cp, int M, int N, int K) {
  __shared__ short As[64][40];
  __shared__ short Bs[64][40];
  int tid = threadIdx.x;
  int m0 = blockIdx.x * 64, n0 = blockIdx.y * 64;
  int w = tid >> 6, lane = tid & 63;
  int wm = w >> 1, wn = w & 1;
  int quad = lane >> 4, l16 = lane & 15;
  f32x4 acc[2][2];
#pragma unroll
  for (int i = 0; i < 2; i++)
#pragma unroll
    for (int j = 0; j < 2; j++) acc[i][j] = (f32x4){0.f, 0.f, 0.f, 0.f};
  int lr = tid >> 2, lk = (tid & 3) * 8;
  for (int kk = 0; kk < K; kk += 32) {
    __syncthreads();
    {
      int rl = m0 + lr;
      if (A_XF32) {
        const float* A = (const float*)Ap;
        size_t phys = ((size_t)(rl & 31) * TT + (rl >> 5)) * K;
        const float4* p = (const float4*)(A + phys + kk + lk);
        float4 a0 = p[0], a1 = p[1];
        short8 v;
        v[0] = f2bf(a0.x); v[1] = f2bf(a0.y); v[2] = f2bf(a0.z); v[3] = f2bf(a0.w);
        v[4] = f2bf(a1.x); v[5] = f2bf(a1.y); v[6] = f2bf(a1.z); v[7] = f2bf(a1.w);
        *(short8*)&As[lr][lk] = v;
      } else {
        const short* A = (const short*)Ap;
        *(short8*)&As[lr][lk] = *(const short8*)(A + (size_t)rl * K + kk + lk);
      }
      *(short8*)&Bs[lr][lk] = *(const short8*)(Bw + (size_t)(n0 + lr) * K + kk + lk);
    }
    __syncthreads();
    short8 af[2], bfr[2];
#pragma unroll
    for (int i = 0; i < 2; i++) af[i] = *(short8*)&As[wm * 32 + i * 16 + l16][quad * 8];
#pragma unroll
    for (int j = 0; j < 2; j++) bfr[j] = *(short8*)&Bs[wn * 32 + j * 16 + l16][quad * 8];
#pragma unroll
    for (int i = 0; i < 2; i++)
#pragma unroll
      for (int j = 0; j < 2; j++)
        acc[i][j] = __builtin_amdgcn_mfma_f32_16x16x32_bf16(af[i], bfr[j], acc[i][j], 0, 0, 0);
  }
#pragma unroll
  for (int i = 0; i < 2; i++) {
#pragma unroll
    for (int j = 0; j < 2; j++) {
#pragma unroll
      for (int rr = 0; rr < 4; rr++) {
        int row = m0 + wm * 32 + i * 16 + quad * 4 + rr;
        int col = n0 + wn * 32 + j * 16 + l16;
        float v2 = acc[i][j][rr] + bias[col];
        if (OUT_SW) {
          int t = row >> 5, b = row & 31;
          int wg2 = b >> 4, bl = b & 15;
          int wv2 = col >> 6, ct2 = (col >> 4) & 3, q2 = (col >> 2) & 3, r2 = col & 3;
          size_t idx = (((((size_t)t * 2 + wg2) * 8 + wv2) * 4 + ct2) * 64 + (q2 * 16 + bl)) * 4 + r2;
          ((short*)Cp)[idx] = f2bf(v2);
        } else {
          size_t idx = ((size_t)(row & 31) * TT + (row >> 5)) * N + col;
          if (RESID) v2 += resid[idx];
          ((float*)Cp)[idx] = v2;
        }
      }
    }
  }
}

// ---------------- single-CU-per-batch-group CT-RNN scan ----------------
// 2 WGs x 512 threads. WG wg owns batches [wg*16,+16), all 512 cols.
// Weights: 48 frags in regs + 16 frags in LDS per wave (r2-proven split).
// Orientation: A=W (m=col), B=h (n=batch) -> thread holds 4 consecutive
// cols per ct: b64 LDS writes + direct reg->global hall stores.
// Per-step barriers are LDS-only (no vmcnt drain).
__global__ __launch_bounds__(512, 2) void seq_scan(
    const short* __restrict__ xin_sw, const short* __restrict__ Wrec,
    const float* __restrict__ tau, short* __restrict__ hall) {
  __shared__ short Wl[8][16][64][8];   // 128 KiB: per-wave LDS weight frags
  __shared__ __align__(16) short hb[16][520];  // h state, bf16
  int wg = blockIdx.x;
  int tid = threadIdx.x;
  int wv = tid >> 6, lane = tid & 63;
  int q = lane >> 4, l16 = lane & 15;
  int c0 = wv * 64;

  for (int i = tid; i < 16 * 520 / 2; i += 512) ((int*)hb)[i] = 0;

  // A-operand frags: frag(ct,kc) = W[col=c0+ct*16+l16][kc*32+q*8 .. +8]
  short8 wreg[48];
#pragma unroll
  for (int ct = 0; ct < 4; ct++) {
    const short* wrow = Wrec + (size_t)(c0 + ct * 16 + l16) * HH;
#pragma unroll
    for (int kc = 0; kc < 12; kc++)
      wreg[ct * 12 + kc] = *(const short8*)(wrow + kc * 32 + q * 8);
#pragma unroll
    for (int kc = 12; kc < 16; kc++)
      *(short8*)&Wl[wv][ct * 4 + (kc - 12)][lane][0] = *(const short8*)(wrow + kc * 32 + q * 8);
  }
  // per-thread rates for its 16 cols (ct,r): col = c0 + ct*16 + q*4 + r
  float rate[16];
#pragma unroll
  for (int ct = 0; ct < 4; ct++)
#pragma unroll
    for (int r = 0; r < 4; r++) {
      float tc = tau[c0 + ct * 16 + q * 4 + r];
      tc = fminf(fmaxf(tc, 0.1f), 10.f);
      rate[ct * 4 + r] = 0.1f / tc;
    }
  float st[16];
#pragma unroll
  for (int i = 0; i < 16; i++) st[i] = 0.f;

  const short* xbase = xin_sw + (size_t)wg * 8192 + wv * 1024 + lane * 4;
  short* hallp = hall + ((size_t)wg * 16 + l16) * HH + c0 + q * 4;

  short4v xrA[4], xrB[4];
#pragma unroll
  for (int ct = 0; ct < 4; ct++) xrA[ct] = *(const short4v*)(xbase + ct * 256);
  __syncthreads();

#define STEP_BODY(T, XU, XP)                                                      \
  {                                                                               \
    int tn = ((T) + 1 < TT) ? (T) + 1 : (T);                                      \
    const short* xp_ = xbase + (size_t)tn * 16384;                                \
    _Pragma("unroll")                                                             \
    for (int ct = 0; ct < 4; ct++) XP[ct] = *(const short4v*)(xp_ + ct * 256);    \
    f32x4 acc[4];                                                                 \
    _Pragma("unroll")                                                             \
    for (int ct = 0; ct < 4; ct++) acc[ct] = (f32x4){0.f, 0.f, 0.f, 0.f};         \
    _Pragma("unroll")                                                             \
    for (int kc = 0; kc < 12; kc++) {                                             \
      short8 af = *(short8*)&hb[l16][kc * 32 + q * 8];                            \
      _Pragma("unroll")                                                           \
      for (int ct = 0; ct < 4; ct++)                                              \
        acc[ct] = __builtin_amdgcn_mfma_f32_16x16x32_bf16(wreg[ct * 12 + kc],     \
                                                          af, acc[ct], 0, 0, 0);  \
    }                                                                             \
    _Pragma("unroll")                                                             \
    for (int kc = 12; kc < 16; kc++) {                                            \
      short8 af = *(short8*)&hb[l16][kc * 32 + q * 8];                            \
      _Pragma("unroll")                                                           \
      for (int ct = 0; ct < 4; ct++) {                                            \
        short8 wf = *(short8*)&Wl[wv][ct * 4 + (kc - 12)][lane][0];               \
        acc[ct] = __builtin_amdgcn_mfma_f32_16x16x32_bf16(wf, af, acc[ct], 0, 0, 0); \
      }                                                                           \
    }                                                                             \
    barrier_lds(); /* all waves done reading hb */                                \
    short* hp_ = hallp + ((size_t)(T) * 32) * HH;                                 \
    _Pragma("unroll")                                                             \
    for (int ct = 0; ct < 4; ct++) {                                              \
      short4v hv;                                                                 \
      _Pragma("unroll")                                                           \
      for (int r = 0; r < 4; r++) {                                               \
        float u = acc[ct][r] + bf2f(XU[ct][r]);                                   \
        float v = u * 2.8853900817779268f;                                        \
        v = fminf(fmaxf(v, -30.f), 30.f);                                         \
        float e = __builtin_amdgcn_exp2f(v);                                      \
        float tg = (e - 1.f) * __builtin_amdgcn_rcpf(e + 1.f);                    \
        float h = st[ct * 4 + r];                                                 \
        h += rate[ct * 4 + r] * (tg - h);                                         \
        st[ct * 4 + r] = h;                                                       \
        hv[r] = f2bf(h);                                                          \
      }                                                                           \
      *(short4v*)&hb[l16][c0 + ct * 16 + q * 4] = hv;                             \
      *(short4v*)(hp_ + ct * 16) = hv;                                            \
    }                                                                             \
    barrier_lds(); /* hb(t+1) complete */                                         \
  }

  for (int t = 0; t < TT; t += 2) {
    STEP_BODY(t, xrA, xrB);
    STEP_BODY(t + 1, xrB, xrA);
  }
#undef STEP_BODY
}

extern "C" void kernel_launch(void* const* d_in, const int* in_sizes, int n_in,
                              void* d_out, int out_size, void* d_ws, size_t ws_size,
                              hipStream_t stream) {
  const float* x      = (const float*)d_in[0];
  const float* W_in0  = (const float*)d_in[1];
  const float* b_in0  = (const float*)d_in[2];
  const float* W_rec0 = (const float*)d_in[3];
  const float* tau0   = (const float*)d_in[4];
  const float* W_in1  = (const float*)d_in[5];
  const float* b_in1  = (const float*)d_in[6];
  const float* W_rec1 = (const float*)d_in[7];
  const float* tau1   = (const float*)d_in[8];
  const float* W_out  = (const float*)d_in[9];
  const float* b_out  = (const float*)d_in[10];

  char* ws = (char*)d_ws;
  short* wb     = (short*)ws;                        // 2 MB bf16 weights
  short* xin_sw = (short*)(ws + (4u << 20));         // 64 MB swizzled xin
  short* hall   = (short*)(ws + (68u << 20));        // 64 MB h stream (t-major)

  short* wbin0  = wb;
  short* wbrec0 = wb + 131072;
  short* wbin1  = wb + 393216;
  short* wbrec1 = wb + 655360;
  short* wbout  = wb + 917504;

  convert_weights<<<4096, 256, 0, stream>>>(W_in0, W_rec0, W_in1, W_rec1, W_out, wb);

  dim3 g1(1024, 8);
  gemm_bt<1, 1, 0><<<g1, 256, 0, stream>>>((const void*)x, wbin0, b_in0, nullptr,
                                           (void*)xin_sw, BB * TT, HH, 256);
  seq_scan<<<2, 512, 0, stream>>>(xin_sw, wbrec0, tau0, hall);
  gemm_bt<0, 1, 0><<<g1, 256, 0, stream>>>((const void*)hall, wbin1, b_in1, nullptr,
                                           (void*)xin_sw, BB * TT, HH, HH);
  seq_scan<<<2, 512, 0, stream>>>(xin_sw, wbrec1, tau1, hall);
  dim3 g2(1024, 4);
  gemm_bt<0, 0, 1><<<g2, 256, 0, stream>>>((const void*)hall, wbout, b_out, x,
                                           d_out, BB * TT, 256, HH);
}